// Round 1
// baseline (863.450 us; speedup 1.0000x reference)
//
#include <hip/hip_runtime.h>
#include <hip/hip_bf16.h>
#include <cstddef>

#define B_ 4
#define S_ 2048
#define D_ 2048
#define H_ 16
#define DH_ 128
#define F_ 6144
#define BS_ 8192

typedef __attribute__((ext_vector_type(8))) short bfrag8;
typedef __attribute__((ext_vector_type(4))) float ffrag4;

__device__ __forceinline__ short f2bf(float f) {
  unsigned u = __float_as_uint(f);
  u = (u + 0x7FFFu + ((u >> 16) & 1u)) >> 16;
  return (short)u;
}
__device__ __forceinline__ float bf2f(short s) {
  return __uint_as_float(((unsigned)(unsigned short)s) << 16);
}

// ---------------- LayerNorm: fp32 X -> bf16 Xn ----------------
__global__ __launch_bounds__(256) void ln_kernel(const float* __restrict__ X,
    const float* __restrict__ w, const float* __restrict__ bta,
    short* __restrict__ Xn) {
  int row = blockIdx.x;
  int tid = threadIdx.x;
  const float* xr = X + (size_t)row * D_;
  float x[8];
  float4 v0 = *(const float4*)(xr + tid * 4);
  float4 v1 = *(const float4*)(xr + 1024 + tid * 4);
  x[0] = v0.x; x[1] = v0.y; x[2] = v0.z; x[3] = v0.w;
  x[4] = v1.x; x[5] = v1.y; x[6] = v1.z; x[7] = v1.w;
  float sum = 0.f, ssq = 0.f;
#pragma unroll
  for (int i = 0; i < 8; i++) { sum += x[i]; ssq += x[i] * x[i]; }
#pragma unroll
  for (int off = 1; off < 64; off <<= 1) {
    sum += __shfl_xor(sum, off, 64);
    ssq += __shfl_xor(ssq, off, 64);
  }
  __shared__ float s1[4], s2[4];
  int wave = tid >> 6;
  if ((tid & 63) == 0) { s1[wave] = sum; s2[wave] = ssq; }
  __syncthreads();
  sum = s1[0] + s1[1] + s1[2] + s1[3];
  ssq = s2[0] + s2[1] + s2[2] + s2[3];
  float mu = sum * (1.0f / D_);
  float var = ssq * (1.0f / D_) - mu * mu;
  float rs = rsqrtf(var + 1e-5f);
  short* orow = Xn + (size_t)row * D_;
#pragma unroll
  for (int i = 0; i < 8; i++) {
    int col = (i < 4) ? (tid * 4 + i) : (1024 + tid * 4 + (i - 4));
    float xn = (x[i] - mu) * rs * w[col] + bta[col];
    orow[col] = f2bf(xn);
  }
}

// ---------------- Transpose + cast: W (RxC fp32) -> WT (CxR bf16) ----------------
__global__ __launch_bounds__(256) void transpose_cvt(const float* __restrict__ W,
    short* __restrict__ WT, int R, int C) {
  __shared__ float t[32][33];
  int tx = threadIdx.x, ty = threadIdx.y;
  int c0 = blockIdx.x * 32, r0 = blockIdx.y * 32;
#pragma unroll
  for (int i = 0; i < 4; i++)
    t[ty + i * 8][tx] = W[(size_t)(r0 + ty + i * 8) * C + c0 + tx];
  __syncthreads();
#pragma unroll
  for (int i = 0; i < 4; i++)
    WT[(size_t)(c0 + ty + i * 8) * R + r0 + tx] = f2bf(t[tx][ty + i * 8]);
}

// ---------------- GEMM: C = A(MxK) * Bt(NxK)^T, bf16 in, MFMA 16x16x32 ----------------
// EPI 0: write bf16 to Cb.  EPI 1: write fp32 Cf = acc + resid.
template<int EPI>
__global__ __launch_bounds__(256) void gemm_bt(const short* __restrict__ A,
    const short* __restrict__ Bt, short* __restrict__ Cb, float* __restrict__ Cf,
    const float* __restrict__ resid, int M, int N, int K) {
  __shared__ __align__(16) short lA[128 * 64];
  __shared__ __align__(16) short lB[128 * 64];
  int tid = threadIdx.x;
  int m0 = blockIdx.y * 128, n0 = blockIdx.x * 128;
  int wave = tid >> 6, lane = tid & 63;
  int m16 = lane & 15, quad = lane >> 4;
  int wm = (wave >> 1) * 64, wn = (wave & 1) * 64;
  const ffrag4 fzero = {0.f, 0.f, 0.f, 0.f};
  ffrag4 acc[4][4];
#pragma unroll
  for (int i = 0; i < 4; i++)
#pragma unroll
    for (int j = 0; j < 4; j++) acc[i][j] = fzero;

  for (int k0 = 0; k0 < K; k0 += 64) {
#pragma unroll
    for (int i = 0; i < 4; i++) {
      int u = tid + i * 256;
      int rr = u >> 3, seg = u & 7;
      int sw = (seg ^ (rr & 7)) << 3;
      *(int4*)(lA + rr * 64 + sw) = *(const int4*)(A + (size_t)(m0 + rr) * K + k0 + seg * 8);
      *(int4*)(lB + rr * 64 + sw) = *(const int4*)(Bt + (size_t)(n0 + rr) * K + k0 + seg * 8);
    }
    __syncthreads();
#pragma unroll
    for (int kk = 0; kk < 2; kk++) {
      bfrag8 af[4], bfb[4];
#pragma unroll
      for (int t = 0; t < 4; t++) {
        int ra = wm + t * 16 + m16;
        int rb = wn + t * 16 + m16;
        int seg = kk * 4 + quad;
        af[t] = *(const bfrag8*)(lA + ra * 64 + ((seg ^ (ra & 7)) << 3));
        bfb[t] = *(const bfrag8*)(lB + rb * 64 + ((seg ^ (rb & 7)) << 3));
      }
#pragma unroll
      for (int i = 0; i < 4; i++)
#pragma unroll
        for (int j = 0; j < 4; j++)
          acc[i][j] = __builtin_amdgcn_mfma_f32_16x16x32_bf16(af[i], bfb[j], acc[i][j], 0, 0, 0);
    }
    __syncthreads();
  }

#pragma unroll
  for (int i = 0; i < 4; i++) {
    int rowb = m0 + wm + i * 16 + quad * 4;
#pragma unroll
    for (int j = 0; j < 4; j++) {
      int col = n0 + wn + j * 16 + m16;
#pragma unroll
      for (int r = 0; r < 4; r++) {
        float v = acc[i][j][r];
        size_t idx = (size_t)(rowb + r) * N + col;
        if (EPI == 0) Cb[idx] = f2bf(v);
        else Cf[idx] = v + resid[idx];
      }
    }
  }
}

// ---------------- RoPE in-place on Q,K halves of qkv ----------------
__global__ __launch_bounds__(256) void rope_kernel(short* __restrict__ qkv) {
  int idx = blockIdx.x * 256 + threadIdx.x;
  int j = idx & 31;
  int h = (idx >> 5) & 15;
  int which = (idx >> 9) & 1;
  int row = idx >> 10;           // b*S + s
  int s = row & (S_ - 1);
  float invf = exp2f(-(float)j * (13.287712379549449f / 32.0f)); // 10000^(-2j/64)
  float ang = (float)s * invf;
  float sn, cs;
  sincosf(ang, &sn, &cs);
  size_t base = (size_t)row * F_ + (size_t)which * D_ + h * DH_ + 2 * j;
  unsigned v = *(unsigned*)(qkv + base);
  float x1 = bf2f((short)(v & 0xFFFF));
  float x2 = bf2f((short)(v >> 16));
  float o1 = x1 * cs - x2 * sn;
  float o2 = x2 * cs + x1 * sn;
  unsigned ov = (unsigned)(unsigned short)f2bf(o1) |
                ((unsigned)(unsigned short)f2bf(o2) << 16);
  *(unsigned*)(qkv + base) = ov;
}

// ---------------- V transpose: qkv V-part -> Vt (b,h,Dh,S) bf16 ----------------
__global__ __launch_bounds__(256) void vtrans_kernel(const short* __restrict__ qkv,
    short* __restrict__ Vt) {
  __shared__ unsigned short t[32][33];
  int tx = threadIdx.x, ty = threadIdx.y;
  int s0 = blockIdx.x * 32;
  int d0 = blockIdx.y * 32;
  int bh = blockIdx.z;
  int b = bh >> 4, h = bh & 15;
#pragma unroll
  for (int i = 0; i < 4; i++)
    t[ty + i * 8][tx] =
      (unsigned short)qkv[(size_t)(b * S_ + s0 + ty + i * 8) * F_ + 2 * D_ + h * DH_ + d0 + tx];
  __syncthreads();
#pragma unroll
  for (int i = 0; i < 4; i++)
    Vt[(size_t)(bh * DH_ + d0 + ty + i * 8) * S_ + s0 + tx] = (short)t[tx][ty + i * 8];
}

// ---------------- Flash attention: q-tile 128 (16 rows/wave), k-tile 128 ----------------
__global__ __launch_bounds__(512) void attn_kernel(const short* __restrict__ qkv,
    const short* __restrict__ Vt, short* __restrict__ ctx) {
  __shared__ __align__(16) short lKV[128 * 128];     // 32 KiB, K then V
  __shared__ __align__(16) short lP[8][16 * 128];    // 32 KiB, per-wave P
  int tid = threadIdx.x;
  int wave = tid >> 6, lane = tid & 63;
  int m16 = lane & 15, quad = lane >> 4;
  int qtile = blockIdx.x, bh = blockIdx.y;
  int b = bh >> 4, h = bh & 15;
  int q0 = qtile * 128;
  int qr = q0 + wave * 16;
  short* lp = &lP[wave][0];

  // Q fragments in registers (A-layout), uncoalesced but once per block
  bfrag8 qf[4];
#pragma unroll
  for (int kc = 0; kc < 4; kc++) {
    const short* p = qkv + (size_t)(b * S_ + qr + m16) * F_ + h * DH_ + kc * 32 + quad * 8;
    qf[kc] = *(const bfrag8*)p;
  }
  float m_i[4], l_i[4];
#pragma unroll
  for (int r = 0; r < 4; r++) { m_i[r] = -1e30f; l_i[r] = 0.f; }
  const ffrag4 fzero = {0.f, 0.f, 0.f, 0.f};
  ffrag4 oacc[8];
#pragma unroll
  for (int n = 0; n < 8; n++) oacc[n] = fzero;
  const float cexp = 0.08838834764831845f * 1.4426950408889634f; // 1/sqrt(128)*log2(e)

  for (int kt = 0; kt < 16; kt++) {
    int sk0 = kt * 128;
    __syncthreads();  // prev PV done with lKV
    // stage K tile [s_k 128][dh 128], xor-swizzled
#pragma unroll
    for (int i = 0; i < 4; i++) {
      int u = tid + i * 512;
      int rr = u >> 4, seg = u & 15;
      *(int4*)(lKV + rr * 128 + ((seg ^ (rr & 15)) << 3)) =
        *(const int4*)(qkv + (size_t)(b * S_ + sk0 + rr) * F_ + D_ + h * DH_ + seg * 8);
    }
    __syncthreads();
    // scores: S = Q * K^T
    ffrag4 sacc[8];
#pragma unroll
    for (int n = 0; n < 8; n++) sacc[n] = fzero;
#pragma unroll
    for (int nt = 0; nt < 8; nt++) {
#pragma unroll
      for (int kc = 0; kc < 4; kc++) {
        int rb = nt * 16 + m16;
        int seg = kc * 4 + quad;
        bfrag8 kf = *(const bfrag8*)(lKV + rb * 128 + ((seg ^ (rb & 15)) << 3));
        sacc[nt] = __builtin_amdgcn_mfma_f32_16x16x32_bf16(qf[kc], kf, sacc[nt], 0, 0, 0);
      }
    }
    // online softmax
    float mnew[4], alpha[4], ps[4];
    float pv[8][4];
#pragma unroll
    for (int r = 0; r < 4; r++) {
      float mx = sacc[0][r];
#pragma unroll
      for (int n = 1; n < 8; n++) mx = fmaxf(mx, sacc[n][r]);
#pragma unroll
      for (int off = 1; off < 16; off <<= 1) mx = fmaxf(mx, __shfl_xor(mx, off, 64));
      mnew[r] = fmaxf(m_i[r], mx);
      alpha[r] = exp2f((m_i[r] - mnew[r]) * cexp);
      ps[r] = 0.f;
    }
#pragma unroll
    for (int n = 0; n < 8; n++)
#pragma unroll
      for (int r = 0; r < 4; r++) {
        float p = exp2f((sacc[n][r] - mnew[r]) * cexp);
        pv[n][r] = p;
        ps[r] += p;
      }
#pragma unroll
    for (int r = 0; r < 4; r++) {
#pragma unroll
      for (int off = 1; off < 16; off <<= 1) ps[r] += __shfl_xor(ps[r], off, 64);
      l_i[r] = l_i[r] * alpha[r] + ps[r];
      m_i[r] = mnew[r];
    }
#pragma unroll
    for (int n = 0; n < 8; n++)
#pragma unroll
      for (int r = 0; r < 4; r++) oacc[n][r] *= alpha[r];
    // write P (C-layout -> LDS, bf16, swizzled)
#pragma unroll
    for (int n = 0; n < 8; n++)
#pragma unroll
      for (int r = 0; r < 4; r++) {
        int rowp = quad * 4 + r;
        int col = n * 16 + m16;
        int seg = col >> 3;
        lp[rowp * 128 + ((seg ^ rowp) << 3) + (col & 7)] = f2bf(pv[n][r]);
      }
    __syncthreads();  // done reading K
    // stage V tile [dh 128][s_k 128] from Vt
#pragma unroll
    for (int i = 0; i < 4; i++) {
      int u = tid + i * 512;
      int rr = u >> 4, seg = u & 15;
      *(int4*)(lKV + rr * 128 + ((seg ^ (rr & 15)) << 3)) =
        *(const int4*)(Vt + (size_t)(bh * DH_ + rr) * S_ + sk0 + seg * 8);
    }
    __syncthreads();
    // O += P * V
#pragma unroll
    for (int kc = 0; kc < 4; kc++) {
      int sega = kc * 4 + quad;
      bfrag8 pf = *(const bfrag8*)(lp + m16 * 128 + ((sega ^ m16) << 3));
#pragma unroll
      for (int n = 0; n < 8; n++) {
        int rv = n * 16 + m16;
        bfrag8 vf = *(const bfrag8*)(lKV + rv * 128 + ((sega ^ (rv & 15)) << 3));
        oacc[n] = __builtin_amdgcn_mfma_f32_16x16x32_bf16(pf, vf, oacc[n], 0, 0, 0);
      }
    }
  }
  // epilogue: ctx[b][s][h*128+col] = O / l
#pragma unroll
  for (int n = 0; n < 8; n++)
#pragma unroll
    for (int r = 0; r < 4; r++) {
      float v = oacc[n][r] / l_i[r];
      int srow = qr + quad * 4 + r;
      int col = h * DH_ + n * 16 + m16;
      ctx[(size_t)(b * S_ + srow) * D_ + col] = f2bf(v);
    }
}

// ---------------- launch ----------------
extern "C" void kernel_launch(void* const* d_in, const int* in_sizes, int n_in,
                              void* d_out, int out_size, void* d_ws, size_t ws_size,
                              hipStream_t stream) {
  const float* X    = (const float*)d_in[0];
  const float* lnw  = (const float*)d_in[1];
  const float* lnb  = (const float*)d_in[2];
  const float* Win  = (const float*)d_in[3];
  const float* Wout = (const float*)d_in[4];
  float* out = (float*)d_out;
  char* ws = (char*)d_ws;
  // workspace layout (bytes)
  short* Xn    = (short*)(ws + 0);          //  32 MiB: 8192x2048 bf16
  short* WinT  = (short*)(ws + 33554432);   //  24 MiB: 6144x2048 bf16
  short* WoutT = (short*)(ws + 58720256);   //   8 MiB: 2048x2048 bf16
  short* qkv   = (short*)(ws + 67108864);   //  96 MiB: 8192x6144 bf16
  short* Vt    = (short*)(ws + 167772160);  //  32 MiB: (b,h,128,2048) bf16
  short* ctx   = (short*)(ws + 201326592);  //  32 MiB: 8192x2048 bf16

  transpose_cvt<<<dim3(192, 64), dim3(32, 8), 0, stream>>>(Win, WinT, 2048, 6144);
  transpose_cvt<<<dim3(64, 64), dim3(32, 8), 0, stream>>>(Wout, WoutT, 2048, 2048);
  ln_kernel<<<8192, 256, 0, stream>>>(X, lnw, lnb, Xn);
  gemm_bt<0><<<dim3(48, 64), 256, 0, stream>>>(Xn, WinT, qkv, nullptr, nullptr, 8192, 6144, 2048);
  rope_kernel<<<32768, 256, 0, stream>>>(qkv);
  vtrans_kernel<<<dim3(64, 4, 64), dim3(32, 8), 0, stream>>>(qkv, Vt);
  attn_kernel<<<dim3(16, 64), 512, 0, stream>>>(qkv, Vt, ctx);
  gemm_bt<1><<<dim3(16, 64), 256, 0, stream>>>(ctx, WoutT, nullptr, out, X, 8192, 2048, 2048);
}

// Round 2
// 727.059 us; speedup vs baseline: 1.1876x; 1.1876x over previous
//
#include <hip/hip_runtime.h>
#include <hip/hip_bf16.h>
#include <cstddef>

#define B_ 4
#define S_ 2048
#define D_ 2048
#define H_ 16
#define DH_ 128
#define F_ 6144
#define BS_ 8192

typedef __attribute__((ext_vector_type(8))) short bfrag8;
typedef __attribute__((ext_vector_type(4))) float ffrag4;

typedef const __attribute__((address_space(1))) void* gptr1;
typedef __attribute__((address_space(3))) void* lptr3;
#define GL16(g, l) __builtin_amdgcn_global_load_lds((gptr1)(g), (lptr3)(l), 16, 0, 0)

__device__ __forceinline__ short f2bf(float f) {
  unsigned u = __float_as_uint(f);
  u = (u + 0x7FFFu + ((u >> 16) & 1u)) >> 16;
  return (short)u;
}
__device__ __forceinline__ float bf2f(short s) {
  return __uint_as_float(((unsigned)(unsigned short)s) << 16);
}
// pack two fp32 -> bf16x2 dword (lo, hi), RNE
__device__ __forceinline__ unsigned pk2(float lo, float hi) {
  unsigned a = __float_as_uint(lo);
  a = (a + 0x7FFFu + ((a >> 16) & 1u)) >> 16;
  unsigned b = __float_as_uint(hi);
  b = (b + 0x7FFFu + ((b >> 16) & 1u)) & 0xFFFF0000u;
  return a | b;
}

// ---------------- LayerNorm: fp32 X -> bf16 Xn ----------------
__global__ __launch_bounds__(256) void ln_kernel(const float* __restrict__ X,
    const float* __restrict__ w, const float* __restrict__ bta,
    short* __restrict__ Xn) {
  int row = blockIdx.x;
  int tid = threadIdx.x;
  const float* xr = X + (size_t)row * D_;
  float x[8];
  float4 v0 = *(const float4*)(xr + tid * 4);
  float4 v1 = *(const float4*)(xr + 1024 + tid * 4);
  x[0] = v0.x; x[1] = v0.y; x[2] = v0.z; x[3] = v0.w;
  x[4] = v1.x; x[5] = v1.y; x[6] = v1.z; x[7] = v1.w;
  float sum = 0.f, ssq = 0.f;
#pragma unroll
  for (int i = 0; i < 8; i++) { sum += x[i]; ssq += x[i] * x[i]; }
#pragma unroll
  for (int off = 1; off < 64; off <<= 1) {
    sum += __shfl_xor(sum, off, 64);
    ssq += __shfl_xor(ssq, off, 64);
  }
  __shared__ float s1[4], s2[4];
  int wave = tid >> 6;
  if ((tid & 63) == 0) { s1[wave] = sum; s2[wave] = ssq; }
  __syncthreads();
  sum = s1[0] + s1[1] + s1[2] + s1[3];
  ssq = s2[0] + s2[1] + s2[2] + s2[3];
  float mu = sum * (1.0f / D_);
  float var = ssq * (1.0f / D_) - mu * mu;
  float rs = rsqrtf(var + 1e-5f);
  short* orow = Xn + (size_t)row * D_;
#pragma unroll
  for (int i = 0; i < 8; i++) {
    int col = (i < 4) ? (tid * 4 + i) : (1024 + tid * 4 + (i - 4));
    float xn = (x[i] - mu) * rs * w[col] + bta[col];
    orow[col] = f2bf(xn);
  }
}

// ---------------- Transpose + cast: W (RxC fp32) -> WT (CxR bf16) ----------------
__global__ __launch_bounds__(256) void transpose_cvt(const float* __restrict__ W,
    short* __restrict__ WT, int R, int C) {
  __shared__ float t[32][33];
  int tx = threadIdx.x, ty = threadIdx.y;
  int c0 = blockIdx.x * 32, r0 = blockIdx.y * 32;
#pragma unroll
  for (int i = 0; i < 4; i++)
    t[ty + i * 8][tx] = W[(size_t)(r0 + ty + i * 8) * C + c0 + tx];
  __syncthreads();
#pragma unroll
  for (int i = 0; i < 4; i++)
    WT[(size_t)(c0 + ty + i * 8) * R + r0 + tx] = f2bf(t[tx][ty + i * 8]);
}

// ---------------- GEMM: C = A(MxK) * Bt(NxK)^T, m97-style global_load_lds ----------------
template<int EPI>
__global__ __launch_bounds__(256) void gemm_bt(const short* __restrict__ A,
    const short* __restrict__ Bt, short* __restrict__ Cb, float* __restrict__ Cf,
    const float* __restrict__ resid, int M, int N, int K) {
  __shared__ __align__(16) short lA[128 * 64];
  __shared__ __align__(16) short lB[128 * 64];
  int tid = threadIdx.x;
  int m0 = blockIdx.y * 128, n0 = blockIdx.x * 128;
  int wave = tid >> 6, lane = tid & 63;
  int m16 = lane & 15, quad = lane >> 4;
  int wm = (wave >> 1) * 64, wn = (wave & 1) * 64;
  const ffrag4 fzero = {0.f, 0.f, 0.f, 0.f};
  ffrag4 acc[4][4];
#pragma unroll
  for (int i = 0; i < 4; i++)
#pragma unroll
    for (int j = 0; j < 4; j++) acc[i][j] = fzero;

  // staging geometry: tile 128 rows x 64 cols bf16 = 16 KiB = 16 chunks of 1 KiB (8 rows)
  int srow = (lane >> 3);        // 0..7 within chunk
  int scb  = lane & 7;           // 16B block 0..7 within row
  for (int k0 = 0; k0 < K; k0 += 64) {
#pragma unroll
    for (int i = 0; i < 4; i++) {
      int c = i * 4 + wave;              // chunk 0..15
      int r = c * 8 + srow;              // row 0..127
      int sb = scb ^ (r & 7);            // global-side swizzle
      GL16(A + (size_t)(m0 + r) * K + k0 + sb * 8, lA + c * 512);
      GL16(Bt + (size_t)(n0 + r) * K + k0 + sb * 8, lB + c * 512);
    }
    __syncthreads();
#pragma unroll
    for (int kk = 0; kk < 2; kk++) {
      bfrag8 af[4], bfb[4];
#pragma unroll
      for (int t = 0; t < 4; t++) {
        int ra = wm + t * 16 + m16;
        int rb = wn + t * 16 + m16;
        int blk = (kk * 4 + quad);
        af[t] = *(const bfrag8*)(lA + ra * 64 + ((blk ^ (m16 & 7)) << 3));
        bfb[t] = *(const bfrag8*)(lB + rb * 64 + ((blk ^ (m16 & 7)) << 3));
      }
#pragma unroll
      for (int i = 0; i < 4; i++)
#pragma unroll
        for (int j = 0; j < 4; j++)
          acc[i][j] = __builtin_amdgcn_mfma_f32_16x16x32_bf16(af[i], bfb[j], acc[i][j], 0, 0, 0);
    }
    __syncthreads();
  }

#pragma unroll
  for (int i = 0; i < 4; i++) {
    int rowb = m0 + wm + i * 16 + quad * 4;
#pragma unroll
    for (int j = 0; j < 4; j++) {
      int col = n0 + wn + j * 16 + m16;
#pragma unroll
      for (int r = 0; r < 4; r++) {
        float v = acc[i][j][r];
        size_t idx = (size_t)(rowb + r) * N + col;
        if (EPI == 0) Cb[idx] = f2bf(v);
        else Cf[idx] = v + resid[idx];
      }
    }
  }
}

// ---------------- RoPE in-place on Q,K halves of qkv ----------------
__global__ __launch_bounds__(256) void rope_kernel(short* __restrict__ qkv) {
  int idx = blockIdx.x * 256 + threadIdx.x;
  int j = idx & 31;
  int h = (idx >> 5) & 15;
  int which = (idx >> 9) & 1;
  int row = idx >> 10;           // b*S + s
  int s = row & (S_ - 1);
  float invf = exp2f(-(float)j * (13.287712379549449f / 32.0f)); // 10000^(-2j/64)
  float ang = (float)s * invf;
  float sn, cs;
  sincosf(ang, &sn, &cs);
  size_t base = (size_t)row * F_ + (size_t)which * D_ + h * DH_ + 2 * j;
  unsigned v = *(unsigned*)(qkv + base);
  float x1 = bf2f((short)(v & 0xFFFF));
  float x2 = bf2f((short)(v >> 16));
  float o1 = x1 * cs - x2 * sn;
  float o2 = x2 * cs + x1 * sn;
  unsigned ov = (unsigned)(unsigned short)f2bf(o1) |
                ((unsigned)(unsigned short)f2bf(o2) << 16);
  *(unsigned*)(qkv + base) = ov;
}

// ---------------- V transpose: qkv V-part -> Vt (b,h,Dh,S) bf16 ----------------
__global__ __launch_bounds__(256) void vtrans_kernel(const short* __restrict__ qkv,
    short* __restrict__ Vt) {
  __shared__ unsigned short t[32][33];
  int tx = threadIdx.x, ty = threadIdx.y;
  int s0 = blockIdx.x * 32;
  int d0 = blockIdx.y * 32;
  int bh = blockIdx.z;
  int b = bh >> 4, h = bh & 15;
#pragma unroll
  for (int i = 0; i < 4; i++)
    t[ty + i * 8][tx] =
      (unsigned short)qkv[(size_t)(b * S_ + s0 + ty + i * 8) * F_ + 2 * D_ + h * DH_ + d0 + tx];
  __syncthreads();
#pragma unroll
  for (int i = 0; i < 4; i++)
    Vt[(size_t)(bh * DH_ + d0 + ty + i * 8) * S_ + s0 + tx] = (short)t[tx][ty + i * 8];
}

// ---------------- Flash attention, S^T form ----------------
// 512 threads = 8 waves; q-block 256 (32 q-rows/wave as 2 q-subblocks of 16);
// k-tile 64, double-buffered K/V staged via global_load_lds; P via permlane swaps.
__global__ __launch_bounds__(512) void attn_kernel(const short* __restrict__ qkv,
    const short* __restrict__ Vt, short* __restrict__ ctx) {
  __shared__ __align__(16) short lK[2][64 * 128];   // [key][d]  16 KiB each
  __shared__ __align__(16) short lV[2][128 * 64];   // [d][key]  16 KiB each
  int tid = threadIdx.x;
  int wave = tid >> 6, lane = tid & 63;
  int m16 = lane & 15, quad = lane >> 4;
  int bh = blockIdx.y;
  int b = bh >> 4, h = bh & 15;
  int qbase = blockIdx.x * 256 + wave * 32;

  // ---- load Q fragments (B-operand layout), pre-scaled by log2(e)/sqrt(Dh) ----
  const float qscale = 1.4426950408889634f * 0.08838834764831845f;
  bfrag8 qf[2][4];
#pragma unroll
  for (int qb = 0; qb < 2; qb++)
#pragma unroll
    for (int kc = 0; kc < 4; kc++) {
      bfrag8 q = *(const bfrag8*)(qkv +
          (size_t)(b * S_ + qbase + qb * 16 + m16) * F_ + h * DH_ + kc * 32 + quad * 8);
#pragma unroll
      for (int j = 0; j < 8; j++) q[j] = f2bf(bf2f(q[j]) * qscale);
      qf[qb][kc] = q;
    }

  const ffrag4 fzero = {0.f, 0.f, 0.f, 0.f};
  ffrag4 oacc[2][8];
#pragma unroll
  for (int qb = 0; qb < 2; qb++)
#pragma unroll
    for (int nd = 0; nd < 8; nd++) oacc[qb][nd] = fzero;
  float lpart[2] = {0.f, 0.f};

  int krow = lane >> 4;          // staging K: row-in-chunk 0..3
  int kcb = lane & 15;           // staging K: 16B dblock 0..15
  int vrow = lane >> 3;          // staging V: row-in-chunk 0..7
  int vcb = lane & 7;            // staging V: 16B keyblock 0..7

  // stage tile 0 into buffer 0
  {
    int sk0 = 0;
#pragma unroll
    for (int i = 0; i < 2; i++) {
      int c = wave + i * 8;
      int r = c * 4 + krow;
      int sb = kcb ^ (r & 15);
      GL16(qkv + (size_t)(b * S_ + sk0 + r) * F_ + D_ + h * DH_ + sb * 8, &lK[0][c * 512]);
    }
#pragma unroll
    for (int i = 0; i < 2; i++) {
      int c = wave + i * 8;
      int r = c * 8 + vrow;
      int sb = vcb ^ (r & 7);
      GL16(Vt + (size_t)(bh * DH_ + r) * S_ + sk0 + sb * 8, &lV[0][c * 512]);
    }
  }
  __syncthreads();

  for (int kt = 0; kt < 32; kt++) {
    int cur = kt & 1;
    if (kt < 31) {  // stage next tile into the other buffer (async)
      int sk0 = (kt + 1) * 64;
      int nb = cur ^ 1;
#pragma unroll
      for (int i = 0; i < 2; i++) {
        int c = wave + i * 8;
        int r = c * 4 + krow;
        int sb = kcb ^ (r & 15);
        GL16(qkv + (size_t)(b * S_ + sk0 + r) * F_ + D_ + h * DH_ + sb * 8, &lK[nb][c * 512]);
      }
#pragma unroll
      for (int i = 0; i < 2; i++) {
        int c = wave + i * 8;
        int r = c * 8 + vrow;
        int sb = vcb ^ (r & 7);
        GL16(Vt + (size_t)(bh * DH_ + r) * S_ + sk0 + sb * 8, &lV[nb][c * 512]);
      }
    }

    const short* kb = &lK[cur][0];
    const short* vb = &lV[cur][0];

    // ---- S^T = K · Q^T : A=K-frag (from LDS), B=Q-frag (regs) ----
    ffrag4 sacc[2][4];
#pragma unroll
    for (int qb = 0; qb < 2; qb++)
#pragma unroll
      for (int ntk = 0; ntk < 4; ntk++) sacc[qb][ntk] = fzero;
#pragma unroll
    for (int ntk = 0; ntk < 4; ntk++)
#pragma unroll
      for (int kc = 0; kc < 4; kc++) {
        bfrag8 kf = *(const bfrag8*)(kb + (ntk * 16 + m16) * 128 +
                                     (((kc * 4 + quad) ^ m16) << 3));
        sacc[0][ntk] = __builtin_amdgcn_mfma_f32_16x16x32_bf16(kf, qf[0][kc], sacc[0][ntk], 0, 0, 0);
        sacc[1][ntk] = __builtin_amdgcn_mfma_f32_16x16x32_bf16(kf, qf[1][kc], sacc[1][ntk], 0, 0, 0);
      }

    // ---- max-free softmax + C-layout -> A-operand via permlane swaps ----
    bfrag8 pA[2][2];
#pragma unroll
    for (int qb = 0; qb < 2; qb++) {
      unsigned Xp[4][2];
      float ls = 0.f;
#pragma unroll
      for (int ntk = 0; ntk < 4; ntk++) {
        float e0 = exp2f(sacc[qb][ntk][0]);
        float e1 = exp2f(sacc[qb][ntk][1]);
        float e2 = exp2f(sacc[qb][ntk][2]);
        float e3 = exp2f(sacc[qb][ntk][3]);
        ls += (e0 + e1) + (e2 + e3);
        Xp[ntk][0] = pk2(e0, e1);
        Xp[ntk][1] = pk2(e2, e3);
      }
      lpart[qb] += ls;
#pragma unroll
      for (int kc = 0; kc < 2; kc++) {
        unsigned x0 = Xp[2 * kc][0], x1 = Xp[2 * kc][1];
        unsigned y0 = Xp[2 * kc + 1][0], y1 = Xp[2 * kc + 1][1];
        asm("v_permlane32_swap_b32 %0, %1" : "+v"(x0), "+v"(y0));
        asm("v_permlane16_swap_b32 %0, %1" : "+v"(x0), "+v"(y0));
        asm("v_permlane32_swap_b32 %0, %1" : "+v"(x1), "+v"(y1));
        asm("v_permlane16_swap_b32 %0, %1" : "+v"(x1), "+v"(y1));
        union { int4 i4; bfrag8 b8; } u;
        u.i4 = (int4){(int)x0, (int)x1, (int)y0, (int)y1};
        pA[qb][kc] = u.b8;
      }
    }

    // ---- O += P · V ----
#pragma unroll
    for (int kc = 0; kc < 2; kc++)
#pragma unroll
      for (int nd = 0; nd < 8; nd++) {
        bfrag8 vf = *(const bfrag8*)(vb + (nd * 16 + m16) * 64 +
                                     (((kc * 4 + quad) ^ (m16 & 7)) << 3));
        oacc[0][nd] = __builtin_amdgcn_mfma_f32_16x16x32_bf16(pA[0][kc], vf, oacc[0][nd], 0, 0, 0);
        oacc[1][nd] = __builtin_amdgcn_mfma_f32_16x16x32_bf16(pA[1][kc], vf, oacc[1][nd], 0, 0, 0);
      }

    __syncthreads();
  }

  // ---- epilogue: l reduce across quads, divide, write ctx ----
#pragma unroll
  for (int qb = 0; qb < 2; qb++) {
    lpart[qb] += __shfl_xor(lpart[qb], 16, 64);
    lpart[qb] += __shfl_xor(lpart[qb], 32, 64);
  }
#pragma unroll
  for (int qb = 0; qb < 2; qb++) {
    float inv[4];
#pragma unroll
    for (int r = 0; r < 4; r++) inv[r] = 1.0f / __shfl(lpart[qb], quad * 4 + r, 64);
#pragma unroll
    for (int nd = 0; nd < 8; nd++)
#pragma unroll
      for (int r = 0; r < 4; r++) {
        int row = qbase + qb * 16 + quad * 4 + r;
        int col = h * DH_ + nd * 16 + m16;
        ctx[(size_t)(b * S_ + row) * D_ + col] = f2bf(oacc[qb][nd][r] * inv[r]);
      }
  }
}

// ---------------- launch ----------------
extern "C" void kernel_launch(void* const* d_in, const int* in_sizes, int n_in,
                              void* d_out, int out_size, void* d_ws, size_t ws_size,
                              hipStream_t stream) {
  const float* X    = (const float*)d_in[0];
  const float* lnw  = (const float*)d_in[1];
  const float* lnb  = (const float*)d_in[2];
  const float* Win  = (const float*)d_in[3];
  const float* Wout = (const float*)d_in[4];
  float* out = (float*)d_out;
  char* ws = (char*)d_ws;
  short* Xn    = (short*)(ws + 0);          //  32 MiB: 8192x2048 bf16
  short* WinT  = (short*)(ws + 33554432);   //  24 MiB: 6144x2048 bf16
  short* WoutT = (short*)(ws + 58720256);   //   8 MiB: 2048x2048 bf16
  short* qkv   = (short*)(ws + 67108864);   //  96 MiB: 8192x6144 bf16
  short* Vt    = (short*)(ws + 167772160);  //  32 MiB: (b,h,128,2048) bf16
  short* ctx   = (short*)(ws + 201326592);  //  32 MiB: 8192x2048 bf16

  transpose_cvt<<<dim3(192, 64), dim3(32, 8), 0, stream>>>(Win, WinT, 2048, 6144);
  transpose_cvt<<<dim3(64, 64), dim3(32, 8), 0, stream>>>(Wout, WoutT, 2048, 2048);
  ln_kernel<<<8192, 256, 0, stream>>>(X, lnw, lnb, Xn);
  gemm_bt<0><<<dim3(48, 64), 256, 0, stream>>>(Xn, WinT, qkv, nullptr, nullptr, 8192, 6144, 2048);
  rope_kernel<<<32768, 256, 0, stream>>>(qkv);
  vtrans_kernel<<<dim3(64, 4, 64), dim3(32, 8), 0, stream>>>(qkv, Vt);
  attn_kernel<<<dim3(8, 64), 512, 0, stream>>>(qkv, Vt, ctx);
  gemm_bt<1><<<dim3(16, 64), 256, 0, stream>>>(ctx, WoutT, nullptr, out, X, 8192, 2048, 2048);
}